// Round 5
// baseline (108.391 us; speedup 1.0000x reference)
//
#include <hip/hip_runtime.h>
#include <math.h>

// ECE loss: per-row softmax-max confidence + argmax prediction, histogram over
// (pred_class, conf_bin) cells, ECE = sum|sum_conf - sum_acc| / N.
//
// Round-5 structure: 1024-thread blocks, 2 blocks/CU -> 32 waves/CU (100%
// occupancy; r3/r4 were at 50%), block-cooperative 64-row tile staging
// (26 KB contiguous bursts like r3), DOUBLE-BUFFERED with raw s_barrier +
// counted s_waitcnt vmcnt(2): loads for tile t+1 stay in flight across the
// barrier and through the consume of tile t (r3's __syncthreads forced a
// vmcnt(0) drain every tile -> zero outstanding loads during every consume).
// Per wave per tile: EXACTLY 2 global_load_lds (exec-uniform: idle lanes
// clamp to an already-fetched line, coalescing to ~1 extra request) so the
// counted vmcnt is identical across waves. Labels are staged INTO the tile
// (16 chunks) so no other VMEM op perturbs the count.
//
// LDS buffer layout (16B chunks), per buffer (2048 chunks = 32 KB):
//   [0 .. 1728)      64 rows x 27 chunks (25 payload + 2 pad for bank spread)
//   [1728 .. 1744)   64 labels (int32)
//   [1744 .. 2048)   junk (writes from clamped idle lanes)
//
// N = 1,000,000 = 64 * 15625 exactly (no row tail).
// Workspace (d_ws as float*): [0..NCELLS) sum_conf, [NCELLS..2*NCELLS) sum_acc.

constexpr int C  = 100;
constexpr int NB = 15;
constexpr int NCELLS = C * NB;        // 1500
constexpr int ROWS = 64;              // rows per tile
constexpr int CHR  = 27;              // LDS chunks (16B) per row
constexpr int TILE_CH = ROWS * CHR;   // 1728
constexpr int LAB_CH0 = TILE_CH;      // label chunks at 1728..1743
constexpr int BUF_CH  = 2048;         // padded buffer size in chunks
constexpr int THREADS = 1024;
constexpr int GRID_MAIN = 512;        // 2 blocks/CU x 256 CU

__global__ void ece_zero(float* __restrict__ ws, int n) {
    int i = blockIdx.x * blockDim.x + threadIdx.x;
    if (i < n) ws[i] = 0.0f;
}

__device__ __forceinline__ void load_lds_16B(const void* gsrc, void* ldst) {
    __builtin_amdgcn_global_load_lds(
        (const __attribute__((address_space(1))) void*)gsrc,
        (__attribute__((address_space(3))) void*)ldst, 16, 0, 0);
}

__global__ __launch_bounds__(THREADS, 8)
void ece_main(const float* __restrict__ logits,
              const int* __restrict__ labels,
              int ntiles, float* __restrict__ cellsums) {
    __shared__ float4 stage[2][BUF_CH];   // 65536 B
    __shared__ float  hist[2 * NCELLS];   // 12000 B -> 77.5 KB, 2 blocks/CU

    for (int i = threadIdx.x; i < 2 * NCELLS; i += THREADS) hist[i] = 0.0f;
    __syncthreads();

    const int tid = threadIdx.x;
    const int h   = tid >> 4;   // row in tile (0..63)
    const int l   = tid & 15;   // lane within hex group

    // ---- per-lane stage descriptors (tile-invariant, bytes from tile base) ----
    // round 0: slot s0 = tid (always a logits chunk; col pad clamps to 24)
    int r0 = tid / CHR, c0 = tid - r0 * CHR;
    if (c0 > 24) c0 = 24;
    const int off0 = (r0 * 25 + c0) * 16;
    // round 1: slot s1 = 1024 + tid: logits chunk | label chunk | junk dup
    const int s1 = 1024 + tid;
    int off1; bool isLab = false;
    if (s1 < TILE_CH) {
        int r = s1 / CHR, c = s1 - r * CHR;
        if (c > 24) c = 24;
        off1 = (r * 25 + c) * 16;
    } else if (s1 < LAB_CH0 + 16) {
        isLab = true;
        off1 = (s1 - LAB_CH0) * 16;      // bytes into this tile's labels
    } else {
        off1 = 0;                         // dup of tile chunk 0 (L1/L2 hit)
    }
    const size_t dstoff = (size_t)(tid & ~63) * 16;  // wave-uniform LDS base

    const char* const lg = (const char*)logits;
    const char* const lb = (const char*)labels;
    constexpr float LOG2E = 1.4426950408889634f;

#define ISSUE_STAGE(T, BUF)                                                   \
    {                                                                         \
        const char* tb_ = lg + (size_t)(T) * (ROWS * C * 4);                  \
        const char* lt_ = lb + (size_t)(T) * (ROWS * 4);                      \
        char* d_ = (char*)&stage[(BUF)][0] + dstoff;                          \
        load_lds_16B(tb_ + off0, d_);                                         \
        const char* s1p_ = isLab ? (lt_ + off1) : (tb_ + off1);               \
        load_lds_16B(s1p_, d_ + 1024 * 16);                                   \
    }

    int t = blockIdx.x;
    int cur = 0;
    if (t < ntiles) ISSUE_STAGE(t, 0);

    for (; t < ntiles; t += GRID_MAIN) {
        const int tn = t + GRID_MAIN;
        if (tn < ntiles) {
            ISSUE_STAGE(tn, cur ^ 1);
            // wait: tile t's 2 loads (oldest) done; tile t+1's 2 stay in flight
            asm volatile("s_waitcnt vmcnt(2)" ::: "memory");
        } else {
            asm volatile("s_waitcnt vmcnt(0)" ::: "memory");
        }
        __builtin_amdgcn_s_barrier();      // raw barrier: NO vmcnt drain
        asm volatile("" ::: "memory");     // fence: no LDS read hoists above

        // ---- consume tile t from stage[cur]: hex(16 lanes) per row ----
        const float4* rp = &stage[cur][h * CHR];
        float4 a = rp[l];                  // chunks 0..15 -> elems 4l..4l+3
        float4 b4;
        const bool two = (l < 9);          // chunks 16..24 -> elems 64+4l..
        if (two) b4 = rp[16 + l];
        const int lab = ((const int*)&stage[cur][LAB_CH0])[h];

        float m = a.x; int am = 4 * l;
        if (a.y > m) { m = a.y; am = 4 * l + 1; }
        if (a.z > m) { m = a.z; am = 4 * l + 2; }
        if (a.w > m) { m = a.w; am = 4 * l + 3; }
        if (two) {
            const int e = 64 + 4 * l;
            if (b4.x > m) { m = b4.x; am = e; }
            if (b4.y > m) { m = b4.y; am = e + 1; }
            if (b4.z > m) { m = b4.z; am = e + 2; }
            if (b4.w > m) { m = b4.w; am = e + 3; }
        }
        #pragma unroll
        for (int off = 1; off < 16; off <<= 1) {
            float om  = __shfl_xor(m, off, 64);
            int   oam = __shfl_xor(am, off, 64);
            if (om > m || (om == m && oam < am)) { m = om; am = oam; }
        }

        const float ml = m * LOG2E;
        float s = exp2f(__fmaf_rn(a.x, LOG2E, -ml))
                + exp2f(__fmaf_rn(a.y, LOG2E, -ml))
                + exp2f(__fmaf_rn(a.z, LOG2E, -ml))
                + exp2f(__fmaf_rn(a.w, LOG2E, -ml));
        if (two) {
            s += exp2f(__fmaf_rn(b4.x, LOG2E, -ml))
               + exp2f(__fmaf_rn(b4.y, LOG2E, -ml))
               + exp2f(__fmaf_rn(b4.z, LOG2E, -ml))
               + exp2f(__fmaf_rn(b4.w, LOG2E, -ml));
        }
        #pragma unroll
        for (int off = 1; off < 16; off <<= 1) s += __shfl_xor(s, off, 64);

        if (l == 0) {
            float conf = 1.0f / s;
            int b = (int)ceilf(conf * (float)NB) - 1;
            b = b < 0 ? 0 : (b > NB - 1 ? NB - 1 : b);
            int cell = am * NB + b;
            atomicAdd(&hist[cell], conf);
            if (lab == am) atomicAdd(&hist[NCELLS + cell], 1.0f);
        }

        // my ds_reads of stage[cur] retired before anyone overwrites it
        asm volatile("s_waitcnt lgkmcnt(0)" ::: "memory");
        __builtin_amdgcn_s_barrier();      // all waves done reading stage[cur]
        asm volatile("" ::: "memory");
        cur ^= 1;
    }
#undef ISSUE_STAGE

    __syncthreads();
    for (int i = threadIdx.x; i < 2 * NCELLS; i += THREADS) {
        float v = hist[i];
        if (v != 0.0f) atomicAdd(&cellsums[i], v);
    }
}

__global__ void ece_final(const float* __restrict__ cellsums,
                          float invN, float* __restrict__ out) {
    __shared__ float red[256];
    float t = 0.0f;
    for (int i = threadIdx.x; i < NCELLS; i += blockDim.x)
        t += fabsf(cellsums[i] - cellsums[NCELLS + i]);
    red[threadIdx.x] = t;
    __syncthreads();
    for (int w = 128; w > 0; w >>= 1) {
        if (threadIdx.x < w) red[threadIdx.x] += red[threadIdx.x + w];
        __syncthreads();
    }
    if (threadIdx.x == 0) out[0] = red[0] * invN;
}

extern "C" void kernel_launch(void* const* d_in, const int* in_sizes, int n_in,
                              void* d_out, int out_size, void* d_ws, size_t ws_size,
                              hipStream_t stream) {
    const float* logits = (const float*)d_in[0];
    const int*   labels = (const int*)d_in[1];

    const int N = in_sizes[1];                 // 1,000,000
    const int ntiles = N / ROWS;               // 15625 (exact)

    float* cellsums = (float*)d_ws;
    float* out = (float*)d_out;

    // 1) zero global cell accumulators (harness poisons ws, never re-zeroes)
    {
        int n = 2 * NCELLS;
        ece_zero<<<(n + 255) / 256, 256, 0, stream>>>(cellsums, n);
    }

    // 2) main pass: double-buffered tile pipeline, raw barriers, counted vmcnt
    ece_main<<<GRID_MAIN, THREADS, 0, stream>>>(logits, labels, ntiles, cellsums);

    // 3) finalize
    ece_final<<<1, 256, 0, stream>>>(cellsums, 1.0f / (float)N, out);
}